// Round 8
// baseline (439.464 us; speedup 1.0000x reference)
//
#include <hip/hip_runtime.h>
#include <stdint.h>

typedef __attribute__((ext_vector_type(8))) short bf16x8;
typedef __attribute__((ext_vector_type(4))) float f32x4;
typedef __attribute__((ext_vector_type(4))) unsigned int u32x4;
typedef __attribute__((ext_vector_type(4))) unsigned short u16x4;

#define DEVINL static __device__ __forceinline__

DEVINL unsigned short f2bf(float f) {
  uint32_t u = __builtin_bit_cast(uint32_t, f);
  u = (u + 0x7FFFu + ((u >> 16) & 1u)) >> 16;
  return (unsigned short)u;
}

DEVINL float fexp2(float x) {
#if __has_builtin(__builtin_amdgcn_exp2f)
  return __builtin_amdgcn_exp2f(x);
#else
  return __expf(x * 0.69314718056f);
#endif
}

// pack 8 fp32 -> 8 bf16 (RNE) via v_cvt_pk_bf16_f32 (register-only asm, T12 primitive)
DEVINL bf16x8 pack8(f32x4 a, f32x4 b) {
  union { uint32_t u[4]; bf16x8 v; } r;
  asm("v_cvt_pk_bf16_f32 %0, %1, %2" : "=v"(r.u[0]) : "v"(a[0]), "v"(a[1]));
  asm("v_cvt_pk_bf16_f32 %0, %1, %2" : "=v"(r.u[1]) : "v"(a[2]), "v"(a[3]));
  asm("v_cvt_pk_bf16_f32 %0, %1, %2" : "=v"(r.u[2]) : "v"(b[0]), "v"(b[1]));
  asm("v_cvt_pk_bf16_f32 %0, %1, %2" : "=v"(r.u[3]) : "v"(b[2]), "v"(b[3]));
  return r.v;
}

// async global->LDS, 16B per lane; lds base must be wave-uniform (lane*16 implicit)
DEVINL void async16(unsigned short* lds, const unsigned short* g) {
  __builtin_amdgcn_global_load_lds(
      (const __attribute__((address_space(1))) unsigned int*)g,
      (__attribute__((address_space(3))) unsigned int*)lds, 16, 0, 0);
}

// ---------------- cast x (fp32 -> bf16), vectorized ----------------
__global__ __launch_bounds__(256) void k_cast_x(const float* __restrict__ in,
                                                unsigned short* __restrict__ out, int n4) {
  int i = blockIdx.x * 256 + threadIdx.x;
  if (i >= n4) return;
  f32x4 v = *(const f32x4*)(in + (size_t)i * 4);
  u16x4 o;
  for (int j = 0; j < 4; ++j) o[j] = f2bf(v[j]);
  *(u16x4*)(out + (size_t)i * 4) = o;
}

// ------------- transpose-cast W: in [K][N] f32 -> out [N][K] bf16 -------------
__global__ __launch_bounds__(256) void k_transpose_w(const float* __restrict__ in,
                                                     unsigned short* __restrict__ out,
                                                     int K, int N) {
  __shared__ unsigned short tile[64][72];
  int k0 = blockIdx.x * 64, n0 = blockIdx.y * 64;
  int t = threadIdx.x;
  int r = t >> 2, c0 = (t & 3) * 16;
  for (int j = 0; j < 4; ++j) {
    int col = c0 + j * 4;
    f32x4 v = *(const f32x4*)(in + (size_t)(k0 + r) * N + n0 + col);
    u16x4 o;
    for (int q = 0; q < 4; ++q) o[q] = f2bf(v[q]);
    *(u16x4*)(&tile[r][col]) = o;
  }
  __syncthreads();
  for (int j = 0; j < 4; ++j) {
    int kcol = c0 + j * 4;
    u16x4 o;
    for (int q = 0; q < 4; ++q) o[q] = tile[kcol + q][r];
    *(u16x4*)(out + (size_t)(n0 + r) * K + k0 + kcol) = o;
  }
}

// ---------------- GEMM: A[M][1024] bf16  x  Bt[N][1024] bf16 ----------------
// m97 structure: global_load_lds width-16 staging, linear LDS, 2-phase.
// MODE 0 epilogue: C-tile -> LDS (dest-layout) -> coalesced 16B stores.
template <int MODE>
__global__ __launch_bounds__(256) void k_gemm(const unsigned short* __restrict__ A,
                                              const unsigned short* __restrict__ Bt,
                                              const float* __restrict__ bias,
                                              unsigned short* __restrict__ Qb,
                                              unsigned short* __restrict__ Kb,
                                              unsigned short* __restrict__ Vt,
                                              float* __restrict__ outF) {
  constexpr int KD = 1024;
  __shared__ unsigned short sh[17408];  // staging (2x 8192) U epilogue tile (128x136)
  unsigned short* lA = sh;
  unsigned short* lB = sh + 8192;
  int tid = threadIdx.x;
  int lane = tid & 63, w = tid >> 6;
  int wr = w >> 1, wc = w & 1;
  int m0 = blockIdx.x * 128, n0 = blockIdx.y * 128;
  int lr = lane & 15, lg = lane >> 4;

  f32x4 acc[4][4] = {};

  int srow = w * 32 + (lane >> 3);
  int scol = (lane & 7) * 8;
  const unsigned short* gA = A + (size_t)(m0 + srow) * KD + scol;
  const unsigned short* gB = Bt + (size_t)(n0 + srow) * KD + scol;

  for (int kk = 0; kk < KD; kk += 64) {
    for (int s = 0; s < 4; ++s) {
      async16(&lA[(w * 32 + s * 8) * 64], gA + (size_t)s * 8 * KD + kk);
      async16(&lB[(w * 32 + s * 8) * 64], gB + (size_t)s * 8 * KD + kk);
    }
    __syncthreads();
    for (int kq = 0; kq < 2; ++kq) {
      bf16x8 af[4], bfr[4];
      for (int i = 0; i < 4; ++i)
        af[i] = *(const bf16x8*)(&lA[(wr * 64 + i * 16 + lr) * 64 + (kq * 4 + lg) * 8]);
      for (int r = 0; r < 4; ++r)
        bfr[r] = *(const bf16x8*)(&lB[(wc * 64 + r * 16 + lr) * 64 + (kq * 4 + lg) * 8]);
      for (int i = 0; i < 4; ++i)
        for (int r = 0; r < 4; ++r)
          acc[i][r] = __builtin_amdgcn_mfma_f32_16x16x32_bf16(af[i], bfr[r], acc[i][r], 0, 0, 0);
    }
    __syncthreads();
  }

  if (MODE == 0) {
    int which = n0 >> 10;
    int head0 = (n0 & 1023) >> 6;
    int b_idx = m0 >> 11;
    int l0 = m0 & 2047;
    if (which < 2) {
      for (int r = 0; r < 4; ++r) {
        int nl = wc * 64 + r * 16 + lr;
        float bv = bias[n0 + nl];
        for (int i = 0; i < 4; ++i) {
          int mlb = wr * 64 + i * 16 + lg * 4;
          for (int jj = 0; jj < 4; ++jj)
            sh[(mlb + jj) * 136 + nl] = f2bf(acc[i][r][jj] + bv);
        }
      }
      __syncthreads();
      unsigned short* dst = (which == 0) ? Qb : Kb;
      for (int it = 0; it < 4; ++it) {
        int row = it * 64 + (tid >> 2);
        int ml = row & 127, hd = row >> 7;
        int c = (tid & 3) * 16;
        bf16x8 v0 = *(const bf16x8*)&sh[ml * 136 + hd * 64 + c];
        bf16x8 v1 = *(const bf16x8*)&sh[ml * 136 + hd * 64 + c + 8];
        size_t bh = (size_t)(b_idx * 16 + head0 + hd);
        size_t off = (bh * 2048 + l0 + ml) * 64 + c;
        *(bf16x8*)(dst + off) = v0;
        *(bf16x8*)(dst + off + 8) = v1;
      }
    } else {
      for (int r = 0; r < 4; ++r) {
        int nl = wc * 64 + r * 16 + lr;
        float bv = bias[n0 + nl];
        for (int i = 0; i < 4; ++i) {
          int mlb = wr * 64 + i * 16 + lg * 4;
          u16x4 pk;
          for (int jj = 0; jj < 4; ++jj) pk[jj] = f2bf(acc[i][r][jj] + bv);
          *(u16x4*)&sh[nl * 136 + mlb] = pk;
        }
      }
      __syncthreads();
      for (int it = 0; it < 4; ++it) {
        int nl = it * 32 + (tid >> 3);
        int c = (tid & 7) * 16;
        bf16x8 v0 = *(const bf16x8*)&sh[nl * 136 + c];
        bf16x8 v1 = *(const bf16x8*)&sh[nl * 136 + c + 8];
        int dk = nl & 63, hd = nl >> 6;
        size_t bh = (size_t)(b_idx * 16 + head0 + hd);
        size_t off = (bh * 64 + dk) * 2048 + l0 + c;
        *(bf16x8*)(Vt + off) = v0;
        *(bf16x8*)(Vt + off + 8) = v1;
      }
    }
  } else {
    for (int r = 0; r < 4; ++r) {
      int n = n0 + wc * 64 + r * 16 + lr;
      float bv = bias[n];
      for (int i = 0; i < 4; ++i) {
        int mb = m0 + wr * 64 + i * 16 + lg * 4;
        for (int jj = 0; jj < 4; ++jj)
          outF[(size_t)(mb + jj) * 1024 + n] = acc[i][r][jj] + bv;
      }
    }
  }
}

// ---------------- fused attention ----------------
// R5-proven numerics (8 waves x 16 q-rows, 512 threads, global K/V fragment
// reads, per-wave fp32 P tile) + R7's XCD-bijective block swizzle:
// bid&7 = XCD, each XCD owns 4 heads -> K/V L2-resident; 4096 waves total
// -> 4 waves/SIMD (vs 2) for latency hiding. VGPR ~48 (R5-measured).
__global__ __launch_bounds__(512) void k_attn(const unsigned short* __restrict__ Qb,
                                              const unsigned short* __restrict__ Kb,
                                              const unsigned short* __restrict__ Vt,
                                              float* __restrict__ attn,
                                              unsigned short* __restrict__ ctx) {
  __shared__ float Pf[8][16 * 68];
  int tid = threadIdx.x, lane = tid & 63, w = tid >> 6;
  int lr = lane & 15, lg = lane >> 4;
  int bid = blockIdx.x;
  int xcd = bid & 7, slot = bid >> 3;
  int bh = xcd * 4 + (slot >> 4);          // 4 heads per XCD -> K/V L2-resident
  int qb = slot & 15;
  int q0 = qb * 128 + w * 16;
  int b_idx = bh >> 4, h = bh & 15;
  const unsigned short* Qh = Qb + (size_t)bh * 2048 * 64;
  const unsigned short* Kh = Kb + (size_t)bh * 2048 * 64;
  const unsigned short* Vh = Vt + (size_t)bh * 64 * 2048;
  float* Pw = &Pf[w][0];
  const float A2 = 0.125f * 1.44269504089f;  // scale * log2(e)

  bf16x8 qf[2];
  for (int kq = 0; kq < 2; ++kq)
    qf[kq] = *(const bf16x8*)(Qh + (size_t)(q0 + lr) * 64 + kq * 32 + lg * 8);

  float l_run[4] = {0.f, 0.f, 0.f, 0.f};

  // ---- pass 1: per-lane partial sum of exp2(s*A2) ----
  for (int kt = 0; kt < 32; ++kt) {
    f32x4 acc[4] = {};
    for (int kq = 0; kq < 2; ++kq) {
      int kof = kq * 32 + lg * 8;
      bf16x8 kf[4];
      for (int r = 0; r < 4; ++r)
        kf[r] = *(const bf16x8*)(Kh + (size_t)(kt * 64 + r * 16 + lr) * 64 + kof);
      for (int r = 0; r < 4; ++r)
        acc[r] = __builtin_amdgcn_mfma_f32_16x16x32_bf16(qf[kq], kf[r], acc[r], 0, 0, 0);
    }
    for (int jj = 0; jj < 4; ++jj)
      l_run[jj] += fexp2(acc[0][jj] * A2) + fexp2(acc[1][jj] * A2) +
                   fexp2(acc[2][jj] * A2) + fexp2(acc[3][jj] * A2);
  }
  float invl[4];
  for (int jj = 0; jj < 4; ++jj) {
    float s = l_run[jj];
    s += __shfl_xor(s, 1);
    s += __shfl_xor(s, 2);
    s += __shfl_xor(s, 4);
    s += __shfl_xor(s, 8);
    invl[jj] = 1.0f / s;
  }

  // ---- pass 2 ----
  f32x4 cacc[4] = {};
  float* attn_base = attn + (size_t)bh * 2048 * 2048;
  float* arow = attn_base + (size_t)(q0 + lg) * 2048 + lr * 4;

  for (int kt = 0; kt < 32; ++kt) {
    f32x4 acc[4] = {};
    for (int kq = 0; kq < 2; ++kq) {
      int kof = kq * 32 + lg * 8;
      bf16x8 kf[4];
      for (int r = 0; r < 4; ++r)
        kf[r] = *(const bf16x8*)(Kh + (size_t)(kt * 64 + r * 16 + lr) * 64 + kof);
      for (int r = 0; r < 4; ++r)
        acc[r] = __builtin_amdgcn_mfma_f32_16x16x32_bf16(qf[kq], kf[r], acc[r], 0, 0, 0);
    }
    // p -> per-wave fp32 LDS tile (2-way bank aliasing = free)
    for (int r = 0; r < 4; ++r) {
      int key = r * 16 + lr;
      for (int jj = 0; jj < 4; ++jj) {
        int rl = lg * 4 + jj;
        Pw[rl * 68 + key] = fexp2(acc[r][jj] * A2) * invl[jj];
      }
    }
    // coalesced attn write: 4 x f32x4 per lane, 256B contiguous per row
    for (int s = 0; s < 4; ++s) {
      f32x4 v = *(const f32x4*)(&Pw[(s * 4 + lg) * 68 + lr * 4]);
      __builtin_nontemporal_store(v, (f32x4*)(arow + (size_t)s * 4 * 2048 + kt * 64));
    }
    // PV: A = P (fp32 tile -> cvt_pk bf16), B = V via V^T (keys contiguous)
    for (int kq2 = 0; kq2 < 2; ++kq2) {
      int kof = kq2 * 32 + lg * 8;
      f32x4 plo = *(const f32x4*)(&Pw[lr * 68 + kof]);
      f32x4 phi = *(const f32x4*)(&Pw[lr * 68 + kof + 4]);
      bf16x8 pa = pack8(plo, phi);
      bf16x8 vf[4];
      for (int nn = 0; nn < 4; ++nn)
        vf[nn] = *(const bf16x8*)(Vh + (size_t)(nn * 16 + lr) * 2048 + kt * 64 + kof);
      for (int nn = 0; nn < 4; ++nn)
        cacc[nn] = __builtin_amdgcn_mfma_f32_16x16x32_bf16(pa, vf[nn], cacc[nn], 0, 0, 0);
    }
  }

  for (int nn = 0; nn < 4; ++nn) {
    int d = nn * 16 + lr;
    for (int jj = 0; jj < 4; ++jj) {
      int q = q0 + lg * 4 + jj;
      int tok = b_idx * 2048 + q;
      ctx[(size_t)tok * 1024 + h * 64 + d] = f2bf(cacc[nn][jj]);
    }
  }
}

extern "C" void kernel_launch(void* const* d_in, const int* in_sizes, int n_in,
                              void* d_out, int out_size, void* d_ws, size_t ws_size,
                              hipStream_t stream) {
  const float* x    = (const float*)d_in[0];
  const float* Wqkv = (const float*)d_in[1];
  const float* bqkv = (const float*)d_in[2];
  const float* Wo   = (const float*)d_in[3];
  const float* bo   = (const float*)d_in[4];
  float* out  = (float*)d_out;
  float* attn = out + (size_t)4096 * 1024;

  char* ws = (char*)d_ws;
  unsigned short* xbf = (unsigned short*)(ws);              //  8 MB  [4096][1024]
  unsigned short* wqT = (unsigned short*)(ws + 8388608);    //  6 MB  [3072][1024]
  unsigned short* woT = (unsigned short*)(ws + 14680064);   //  2 MB  [1024][1024]
  unsigned short* Qb  = (unsigned short*)(ws + 16777216);   //  8 MB  [32][2048][64]
  unsigned short* Kb  = (unsigned short*)(ws + 25165824);   //  8 MB  [32][2048][64]
  unsigned short* Vt  = (unsigned short*)(ws + 33554432);   //  8 MB  [32][64][2048]
  unsigned short* ctx = (unsigned short*)(ws + 41943040);   //  8 MB  [4096][1024]

  k_cast_x<<<dim3(4096), dim3(256), 0, stream>>>(x, xbf, 1048576);
  k_transpose_w<<<dim3(16, 48), dim3(256), 0, stream>>>(Wqkv, wqT, 1024, 3072);
  k_transpose_w<<<dim3(16, 16), dim3(256), 0, stream>>>(Wo, woT, 1024, 1024);
  k_gemm<0><<<dim3(32, 24), dim3(256), 0, stream>>>(xbf, wqT, bqkv, Qb, Kb, Vt, nullptr);
  k_attn<<<dim3(512), dim3(512), 0, stream>>>(Qb, Kb, Vt, attn, ctx);
  k_gemm<1><<<dim3(32, 8), dim3(256), 0, stream>>>(ctx, woT, bo, nullptr, nullptr, nullptr, out);
}

// Round 9
// 330.300 us; speedup vs baseline: 1.3305x; 1.3305x over previous
//
#include <hip/hip_runtime.h>
#include <stdint.h>

typedef __attribute__((ext_vector_type(8))) short bf16x8;
typedef __attribute__((ext_vector_type(4))) float f32x4;
typedef __attribute__((ext_vector_type(4))) unsigned int u32x4;
typedef __attribute__((ext_vector_type(4))) unsigned short u16x4;

#define DEVINL static __device__ __forceinline__

DEVINL unsigned short f2bf(float f) {
  uint32_t u = __builtin_bit_cast(uint32_t, f);
  u = (u + 0x7FFFu + ((u >> 16) & 1u)) >> 16;
  return (unsigned short)u;
}

DEVINL float fexp2(float x) {
#if __has_builtin(__builtin_amdgcn_exp2f)
  return __builtin_amdgcn_exp2f(x);
#else
  return __expf(x * 0.69314718056f);
#endif
}

// pack 8 fp32 -> 8 bf16 (RNE) via v_cvt_pk_bf16_f32 (register-only asm, T12 primitive)
DEVINL bf16x8 pack8(f32x4 a, f32x4 b) {
  union { uint32_t u[4]; bf16x8 v; } r;
  asm("v_cvt_pk_bf16_f32 %0, %1, %2" : "=v"(r.u[0]) : "v"(a[0]), "v"(a[1]));
  asm("v_cvt_pk_bf16_f32 %0, %1, %2" : "=v"(r.u[1]) : "v"(a[2]), "v"(a[3]));
  asm("v_cvt_pk_bf16_f32 %0, %1, %2" : "=v"(r.u[2]) : "v"(b[0]), "v"(b[1]));
  asm("v_cvt_pk_bf16_f32 %0, %1, %2" : "=v"(r.u[3]) : "v"(b[2]), "v"(b[3]));
  return r.v;
}

// async global->LDS, 16B per lane; lds base must be wave-uniform (lane*16 implicit)
DEVINL void async16(unsigned short* lds, const unsigned short* g) {
  __builtin_amdgcn_global_load_lds(
      (const __attribute__((address_space(1))) unsigned int*)g,
      (__attribute__((address_space(3))) unsigned int*)lds, 16, 0, 0);
}

// ---------------- cast x (fp32 -> bf16), vectorized ----------------
__global__ __launch_bounds__(256) void k_cast_x(const float* __restrict__ in,
                                                unsigned short* __restrict__ out, int n4) {
  int i = blockIdx.x * 256 + threadIdx.x;
  if (i >= n4) return;
  f32x4 v = *(const f32x4*)(in + (size_t)i * 4);
  u16x4 o;
  for (int j = 0; j < 4; ++j) o[j] = f2bf(v[j]);
  *(u16x4*)(out + (size_t)i * 4) = o;
}

// ------------- transpose-cast W: in [K][N] f32 -> out [N][K] bf16 -------------
__global__ __launch_bounds__(256) void k_transpose_w(const float* __restrict__ in,
                                                     unsigned short* __restrict__ out,
                                                     int K, int N) {
  __shared__ unsigned short tile[64][72];
  int k0 = blockIdx.x * 64, n0 = blockIdx.y * 64;
  int t = threadIdx.x;
  int r = t >> 2, c0 = (t & 3) * 16;
  for (int j = 0; j < 4; ++j) {
    int col = c0 + j * 4;
    f32x4 v = *(const f32x4*)(in + (size_t)(k0 + r) * N + n0 + col);
    u16x4 o;
    for (int q = 0; q < 4; ++q) o[q] = f2bf(v[q]);
    *(u16x4*)(&tile[r][col]) = o;
  }
  __syncthreads();
  for (int j = 0; j < 4; ++j) {
    int kcol = c0 + j * 4;
    u16x4 o;
    for (int q = 0; q < 4; ++q) o[q] = tile[kcol + q][r];
    *(u16x4*)(out + (size_t)(n0 + r) * K + k0 + kcol) = o;
  }
}

// ---------------- GEMM: A[M][1024] bf16  x  Bt[N][1024] bf16 ----------------
// m97 structure: global_load_lds width-16 staging, linear LDS, 2-phase.
// MODE 0 epilogue: C-tile -> LDS (dest-layout) -> coalesced 16B stores.
template <int MODE>
__global__ __launch_bounds__(256) void k_gemm(const unsigned short* __restrict__ A,
                                              const unsigned short* __restrict__ Bt,
                                              const float* __restrict__ bias,
                                              unsigned short* __restrict__ Qb,
                                              unsigned short* __restrict__ Kb,
                                              unsigned short* __restrict__ Vt,
                                              float* __restrict__ outF) {
  constexpr int KD = 1024;
  __shared__ unsigned short sh[17408];  // staging (2x 8192) U epilogue tile (128x136)
  unsigned short* lA = sh;
  unsigned short* lB = sh + 8192;
  int tid = threadIdx.x;
  int lane = tid & 63, w = tid >> 6;
  int wr = w >> 1, wc = w & 1;
  int m0 = blockIdx.x * 128, n0 = blockIdx.y * 128;
  int lr = lane & 15, lg = lane >> 4;

  f32x4 acc[4][4] = {};

  int srow = w * 32 + (lane >> 3);
  int scol = (lane & 7) * 8;
  const unsigned short* gA = A + (size_t)(m0 + srow) * KD + scol;
  const unsigned short* gB = Bt + (size_t)(n0 + srow) * KD + scol;

  for (int kk = 0; kk < KD; kk += 64) {
    for (int s = 0; s < 4; ++s) {
      async16(&lA[(w * 32 + s * 8) * 64], gA + (size_t)s * 8 * KD + kk);
      async16(&lB[(w * 32 + s * 8) * 64], gB + (size_t)s * 8 * KD + kk);
    }
    __syncthreads();
    for (int kq = 0; kq < 2; ++kq) {
      bf16x8 af[4], bfr[4];
      for (int i = 0; i < 4; ++i)
        af[i] = *(const bf16x8*)(&lA[(wr * 64 + i * 16 + lr) * 64 + (kq * 4 + lg) * 8]);
      for (int r = 0; r < 4; ++r)
        bfr[r] = *(const bf16x8*)(&lB[(wc * 64 + r * 16 + lr) * 64 + (kq * 4 + lg) * 8]);
      for (int i = 0; i < 4; ++i)
        for (int r = 0; r < 4; ++r)
          acc[i][r] = __builtin_amdgcn_mfma_f32_16x16x32_bf16(af[i], bfr[r], acc[i][r], 0, 0, 0);
    }
    __syncthreads();
  }

  if (MODE == 0) {
    int which = n0 >> 10;
    int head0 = (n0 & 1023) >> 6;
    int b_idx = m0 >> 11;
    int l0 = m0 & 2047;
    if (which < 2) {
      for (int r = 0; r < 4; ++r) {
        int nl = wc * 64 + r * 16 + lr;
        float bv = bias[n0 + nl];
        for (int i = 0; i < 4; ++i) {
          int mlb = wr * 64 + i * 16 + lg * 4;
          for (int jj = 0; jj < 4; ++jj)
            sh[(mlb + jj) * 136 + nl] = f2bf(acc[i][r][jj] + bv);
        }
      }
      __syncthreads();
      unsigned short* dst = (which == 0) ? Qb : Kb;
      for (int it = 0; it < 4; ++it) {
        int row = it * 64 + (tid >> 2);
        int ml = row & 127, hd = row >> 7;
        int c = (tid & 3) * 16;
        bf16x8 v0 = *(const bf16x8*)&sh[ml * 136 + hd * 64 + c];
        bf16x8 v1 = *(const bf16x8*)&sh[ml * 136 + hd * 64 + c + 8];
        size_t bh = (size_t)(b_idx * 16 + head0 + hd);
        size_t off = (bh * 2048 + l0 + ml) * 64 + c;
        *(bf16x8*)(dst + off) = v0;
        *(bf16x8*)(dst + off + 8) = v1;
      }
    } else {
      for (int r = 0; r < 4; ++r) {
        int nl = wc * 64 + r * 16 + lr;
        float bv = bias[n0 + nl];
        for (int i = 0; i < 4; ++i) {
          int mlb = wr * 64 + i * 16 + lg * 4;
          u16x4 pk;
          for (int jj = 0; jj < 4; ++jj) pk[jj] = f2bf(acc[i][r][jj] + bv);
          *(u16x4*)&sh[nl * 136 + mlb] = pk;
        }
      }
      __syncthreads();
      for (int it = 0; it < 4; ++it) {
        int nl = it * 32 + (tid >> 3);
        int c = (tid & 7) * 16;
        bf16x8 v0 = *(const bf16x8*)&sh[nl * 136 + c];
        bf16x8 v1 = *(const bf16x8*)&sh[nl * 136 + c + 8];
        int dk = nl & 63, hd = nl >> 6;
        size_t bh = (size_t)(b_idx * 16 + head0 + hd);
        size_t off = (bh * 64 + dk) * 2048 + l0 + c;
        *(bf16x8*)(Vt + off) = v0;
        *(bf16x8*)(Vt + off + 8) = v1;
      }
    }
  } else {
    for (int r = 0; r < 4; ++r) {
      int n = n0 + wc * 64 + r * 16 + lr;
      float bv = bias[n];
      for (int i = 0; i < 4; ++i) {
        int mb = m0 + wr * 64 + i * 16 + lg * 4;
        for (int jj = 0; jj < 4; ++jj)
          outF[(size_t)(mb + jj) * 1024 + n] = acc[i][r][jj] + bv;
      }
    }
  }
}

// ---------------- fused attention ----------------
// R7 structure (4 waves x 32 q-rows, XCD-bijective swizzle) with PLAIN stores
// (no nontemporal hint): A/B test of the nt-store write-path hypothesis.
__global__ __launch_bounds__(256) void k_attn(const unsigned short* __restrict__ Qb,
                                              const unsigned short* __restrict__ Kb,
                                              const unsigned short* __restrict__ Vt,
                                              float* __restrict__ attn,
                                              unsigned short* __restrict__ ctx) {
  __shared__ float Pf[4][32 * 68];
  int tid = threadIdx.x, lane = tid & 63, w = tid >> 6;
  int lr = lane & 15, lg = lane >> 4;
  int bid = blockIdx.x;
  int xcd = bid & 7, slot = bid >> 3;
  int bh = xcd * 4 + (slot >> 4);          // 4 heads per XCD -> K/V L2-resident
  int qb = slot & 15;
  int q0 = qb * 128 + w * 32;
  int b_idx = bh >> 4, h = bh & 15;
  const unsigned short* Qh = Qb + (size_t)bh * 2048 * 64;
  const unsigned short* Kh = Kb + (size_t)bh * 2048 * 64;
  const unsigned short* Vh = Vt + (size_t)bh * 64 * 2048;
  float* Pw = &Pf[w][0];
  const float A2 = 0.125f * 1.44269504089f;  // scale * log2(e)

  bf16x8 qf[2][2];
  for (int i = 0; i < 2; ++i)
    for (int kq = 0; kq < 2; ++kq)
      qf[i][kq] = *(const bf16x8*)(Qh + (size_t)(q0 + i * 16 + lr) * 64 + kq * 32 + lg * 8);

  float l_run[8] = {0.f, 0.f, 0.f, 0.f, 0.f, 0.f, 0.f, 0.f};

  // ---- pass 1: per-lane partial sum of exp2(s*A2) ----
  for (int kt = 0; kt < 32; ++kt) {
    f32x4 acc[2][4] = {};
    for (int kq = 0; kq < 2; ++kq) {
      int kof = kq * 32 + lg * 8;
      bf16x8 kf[4];
      for (int r = 0; r < 4; ++r)
        kf[r] = *(const bf16x8*)(Kh + (size_t)(kt * 64 + r * 16 + lr) * 64 + kof);
      for (int i = 0; i < 2; ++i)
        for (int r = 0; r < 4; ++r)
          acc[i][r] = __builtin_amdgcn_mfma_f32_16x16x32_bf16(qf[i][kq], kf[r], acc[i][r], 0, 0, 0);
    }
    for (int i = 0; i < 2; ++i)
      for (int jj = 0; jj < 4; ++jj) {
        int z = i * 4 + jj;
        l_run[z] += fexp2(acc[i][0][jj] * A2) + fexp2(acc[i][1][jj] * A2) +
                    fexp2(acc[i][2][jj] * A2) + fexp2(acc[i][3][jj] * A2);
      }
  }
  float invl[8];
  for (int z = 0; z < 8; ++z) {
    float s = l_run[z];
    s += __shfl_xor(s, 1);
    s += __shfl_xor(s, 2);
    s += __shfl_xor(s, 4);
    s += __shfl_xor(s, 8);
    invl[z] = 1.0f / s;
  }

  // ---- pass 2 ----
  f32x4 cacc[2][4] = {};
  float* attn_base = attn + (size_t)bh * 2048 * 2048;
  float* arow = attn_base + (size_t)(q0 + lg) * 2048 + lr * 4;  // row base for readback stores

  for (int kt = 0; kt < 32; ++kt) {
    f32x4 acc[2][4] = {};
    for (int kq = 0; kq < 2; ++kq) {
      int kof = kq * 32 + lg * 8;
      bf16x8 kf[4];
      for (int r = 0; r < 4; ++r)
        kf[r] = *(const bf16x8*)(Kh + (size_t)(kt * 64 + r * 16 + lr) * 64 + kof);
      for (int i = 0; i < 2; ++i)
        for (int r = 0; r < 4; ++r)
          acc[i][r] = __builtin_amdgcn_mfma_f32_16x16x32_bf16(qf[i][kq], kf[r], acc[i][r], 0, 0, 0);
    }
    // p -> fp32 LDS tile (2-way bank conflict = free)
    for (int i = 0; i < 2; ++i)
      for (int r = 0; r < 4; ++r) {
        int key = r * 16 + lr;
        for (int jj = 0; jj < 4; ++jj) {
          int z = i * 4 + jj;
          int rl = i * 16 + lg * 4 + jj;
          Pw[rl * 68 + key] = fexp2(acc[i][r][jj] * A2) * invl[z];
        }
      }
    // coalesced attn write: 8 x f32x4 per lane, 256B contiguous per row (PLAIN stores)
    for (int s = 0; s < 8; ++s) {
      f32x4 v = *(const f32x4*)(&Pw[(s * 4 + lg) * 68 + lr * 4]);
      *(f32x4*)(arow + (size_t)s * 4 * 2048 + kt * 64) = v;
    }
    // PV: A = P (fp32 tile -> cvt_pk bf16), B = V via V^T (keys contiguous)
    for (int kq2 = 0; kq2 < 2; ++kq2) {
      int kof = kq2 * 32 + lg * 8;
      bf16x8 pa[2], vf[4];
      for (int i = 0; i < 2; ++i) {
        f32x4 plo = *(const f32x4*)(&Pw[(i * 16 + lr) * 68 + kof]);
        f32x4 phi = *(const f32x4*)(&Pw[(i * 16 + lr) * 68 + kof + 4]);
        pa[i] = pack8(plo, phi);
      }
      for (int nn = 0; nn < 4; ++nn)
        vf[nn] = *(const bf16x8*)(Vh + (size_t)(nn * 16 + lr) * 2048 + kt * 64 + kof);
      for (int i = 0; i < 2; ++i)
        for (int nn = 0; nn < 4; ++nn)
          cacc[i][nn] = __builtin_amdgcn_mfma_f32_16x16x32_bf16(pa[i], vf[nn], cacc[i][nn], 0, 0, 0);
    }
  }

  for (int nn = 0; nn < 4; ++nn) {
    int d = nn * 16 + lr;
    for (int i = 0; i < 2; ++i)
      for (int jj = 0; jj < 4; ++jj) {
        int q = q0 + i * 16 + lg * 4 + jj;
        int tok = b_idx * 2048 + q;
        ctx[(size_t)tok * 1024 + h * 64 + d] = f2bf(cacc[i][nn][jj]);
      }
  }
}

extern "C" void kernel_launch(void* const* d_in, const int* in_sizes, int n_in,
                              void* d_out, int out_size, void* d_ws, size_t ws_size,
                              hipStream_t stream) {
  const float* x    = (const float*)d_in[0];
  const float* Wqkv = (const float*)d_in[1];
  const float* bqkv = (const float*)d_in[2];
  const float* Wo   = (const float*)d_in[3];
  const float* bo   = (const float*)d_in[4];
  float* out  = (float*)d_out;
  float* attn = out + (size_t)4096 * 1024;

  char* ws = (char*)d_ws;
  unsigned short* xbf = (unsigned short*)(ws);              //  8 MB  [4096][1024]
  unsigned short* wqT = (unsigned short*)(ws + 8388608);    //  6 MB  [3072][1024]
  unsigned short* woT = (unsigned short*)(ws + 14680064);   //  2 MB  [1024][1024]
  unsigned short* Qb  = (unsigned short*)(ws + 16777216);   //  8 MB  [32][2048][64]
  unsigned short* Kb  = (unsigned short*)(ws + 25165824);   //  8 MB  [32][2048][64]
  unsigned short* Vt  = (unsigned short*)(ws + 33554432);   //  8 MB  [32][64][2048]
  unsigned short* ctx = (unsigned short*)(ws + 41943040);   //  8 MB  [4096][1024]

  k_cast_x<<<dim3(4096), dim3(256), 0, stream>>>(x, xbf, 1048576);
  k_transpose_w<<<dim3(16, 48), dim3(256), 0, stream>>>(Wqkv, wqT, 1024, 3072);
  k_transpose_w<<<dim3(16, 16), dim3(256), 0, stream>>>(Wo, woT, 1024, 1024);
  k_gemm<0><<<dim3(32, 24), dim3(256), 0, stream>>>(xbf, wqT, bqkv, Qb, Kb, Vt, nullptr);
  k_attn<<<dim3(512), dim3(256), 0, stream>>>(Qb, Kb, Vt, attn, ctx);
  k_gemm<1><<<dim3(32, 8), dim3(256), 0, stream>>>(ctx, woT, bo, nullptr, nullptr, nullptr, out);
}

// Round 10
// 285.838 us; speedup vs baseline: 1.5375x; 1.1556x over previous
//
#include <hip/hip_runtime.h>
#include <stdint.h>

typedef __attribute__((ext_vector_type(8))) short bf16x8;
typedef __attribute__((ext_vector_type(4))) float f32x4;
typedef __attribute__((ext_vector_type(4))) unsigned int u32x4;
typedef __attribute__((ext_vector_type(4))) unsigned short u16x4;

#define DEVINL static __device__ __forceinline__

DEVINL unsigned short f2bf(float f) {
  uint32_t u = __builtin_bit_cast(uint32_t, f);
  u = (u + 0x7FFFu + ((u >> 16) & 1u)) >> 16;
  return (unsigned short)u;
}

DEVINL float fexp2(float x) {
#if __has_builtin(__builtin_amdgcn_exp2f)
  return __builtin_amdgcn_exp2f(x);
#else
  return __expf(x * 0.69314718056f);
#endif
}

// pack 8 fp32 -> 8 bf16 (RNE) via v_cvt_pk_bf16_f32 (register-only asm)
DEVINL bf16x8 pack8(f32x4 a, f32x4 b) {
  union { uint32_t u[4]; bf16x8 v; } r;
  asm("v_cvt_pk_bf16_f32 %0, %1, %2" : "=v"(r.u[0]) : "v"(a[0]), "v"(a[1]));
  asm("v_cvt_pk_bf16_f32 %0, %1, %2" : "=v"(r.u[1]) : "v"(a[2]), "v"(a[3]));
  asm("v_cvt_pk_bf16_f32 %0, %1, %2" : "=v"(r.u[2]) : "v"(b[0]), "v"(b[1]));
  asm("v_cvt_pk_bf16_f32 %0, %1, %2" : "=v"(r.u[3]) : "v"(b[2]), "v"(b[3]));
  return r.v;
}

// async global->LDS, 16B per lane; lds base must be wave-uniform (lane*16 implicit)
DEVINL void async16(unsigned short* lds, const unsigned short* g) {
  __builtin_amdgcn_global_load_lds(
      (const __attribute__((address_space(1))) unsigned int*)g,
      (__attribute__((address_space(3))) unsigned int*)lds, 16, 0, 0);
}

// ---------------- cast x (fp32 -> bf16), vectorized ----------------
__global__ __launch_bounds__(256) void k_cast_x(const float* __restrict__ in,
                                                unsigned short* __restrict__ out, int n4) {
  int i = blockIdx.x * 256 + threadIdx.x;
  if (i >= n4) return;
  f32x4 v = *(const f32x4*)(in + (size_t)i * 4);
  u16x4 o;
  for (int j = 0; j < 4; ++j) o[j] = f2bf(v[j]);
  *(u16x4*)(out + (size_t)i * 4) = o;
}

// ------------- transpose-cast W: in [K][N] f32 -> out [N][K] bf16 -------------
__global__ __launch_bounds__(256) void k_transpose_w(const float* __restrict__ in,
                                                     unsigned short* __restrict__ out,
                                                     int K, int N) {
  __shared__ unsigned short tile[64][72];
  int k0 = blockIdx.x * 64, n0 = blockIdx.y * 64;
  int t = threadIdx.x;
  int r = t >> 2, c0 = (t & 3) * 16;
  for (int j = 0; j < 4; ++j) {
    int col = c0 + j * 4;
    f32x4 v = *(const f32x4*)(in + (size_t)(k0 + r) * N + n0 + col);
    u16x4 o;
    for (int q = 0; q < 4; ++q) o[q] = f2bf(v[q]);
    *(u16x4*)(&tile[r][col]) = o;
  }
  __syncthreads();
  for (int j = 0; j < 4; ++j) {
    int kcol = c0 + j * 4;
    u16x4 o;
    for (int q = 0; q < 4; ++q) o[q] = tile[kcol + q][r];
    *(u16x4*)(out + (size_t)(n0 + r) * K + k0 + kcol) = o;
  }
}

// ---------------- GEMM: A[M][1024] bf16  x  Bt[N][1024] bf16 ----------------
template <int MODE>
__global__ __launch_bounds__(256) void k_gemm(const unsigned short* __restrict__ A,
                                              const unsigned short* __restrict__ Bt,
                                              const float* __restrict__ bias,
                                              unsigned short* __restrict__ Qb,
                                              unsigned short* __restrict__ Kb,
                                              unsigned short* __restrict__ Vt,
                                              float* __restrict__ outF) {
  constexpr int KD = 1024;
  __shared__ unsigned short sh[17408];
  unsigned short* lA = sh;
  unsigned short* lB = sh + 8192;
  int tid = threadIdx.x;
  int lane = tid & 63, w = tid >> 6;
  int wr = w >> 1, wc = w & 1;
  int m0 = blockIdx.x * 128, n0 = blockIdx.y * 128;
  int lr = lane & 15, lg = lane >> 4;

  f32x4 acc[4][4] = {};

  int srow = w * 32 + (lane >> 3);
  int scol = (lane & 7) * 8;
  const unsigned short* gA = A + (size_t)(m0 + srow) * KD + scol;
  const unsigned short* gB = Bt + (size_t)(n0 + srow) * KD + scol;

  for (int kk = 0; kk < KD; kk += 64) {
    for (int s = 0; s < 4; ++s) {
      async16(&lA[(w * 32 + s * 8) * 64], gA + (size_t)s * 8 * KD + kk);
      async16(&lB[(w * 32 + s * 8) * 64], gB + (size_t)s * 8 * KD + kk);
    }
    __syncthreads();
    for (int kq = 0; kq < 2; ++kq) {
      bf16x8 af[4], bfr[4];
      for (int i = 0; i < 4; ++i)
        af[i] = *(const bf16x8*)(&lA[(wr * 64 + i * 16 + lr) * 64 + (kq * 4 + lg) * 8]);
      for (int r = 0; r < 4; ++r)
        bfr[r] = *(const bf16x8*)(&lB[(wc * 64 + r * 16 + lr) * 64 + (kq * 4 + lg) * 8]);
      for (int i = 0; i < 4; ++i)
        for (int r = 0; r < 4; ++r)
          acc[i][r] = __builtin_amdgcn_mfma_f32_16x16x32_bf16(af[i], bfr[r], acc[i][r], 0, 0, 0);
    }
    __syncthreads();
  }

  if (MODE == 0) {
    int which = n0 >> 10;
    int head0 = (n0 & 1023) >> 6;
    int b_idx = m0 >> 11;
    int l0 = m0 & 2047;
    if (which < 2) {
      for (int r = 0; r < 4; ++r) {
        int nl = wc * 64 + r * 16 + lr;
        float bv = bias[n0 + nl];
        for (int i = 0; i < 4; ++i) {
          int mlb = wr * 64 + i * 16 + lg * 4;
          for (int jj = 0; jj < 4; ++jj)
            sh[(mlb + jj) * 136 + nl] = f2bf(acc[i][r][jj] + bv);
        }
      }
      __syncthreads();
      unsigned short* dst = (which == 0) ? Qb : Kb;
      for (int it = 0; it < 4; ++it) {
        int row = it * 64 + (tid >> 2);
        int ml = row & 127, hd = row >> 7;
        int c = (tid & 3) * 16;
        bf16x8 v0 = *(const bf16x8*)&sh[ml * 136 + hd * 64 + c];
        bf16x8 v1 = *(const bf16x8*)&sh[ml * 136 + hd * 64 + c + 8];
        size_t bh = (size_t)(b_idx * 16 + head0 + hd);
        size_t off = (bh * 2048 + l0 + ml) * 64 + c;
        *(bf16x8*)(dst + off) = v0;
        *(bf16x8*)(dst + off + 8) = v1;
      }
    } else {
      for (int r = 0; r < 4; ++r) {
        int nl = wc * 64 + r * 16 + lr;
        float bv = bias[n0 + nl];
        for (int i = 0; i < 4; ++i) {
          int mlb = wr * 64 + i * 16 + lg * 4;
          u16x4 pk;
          for (int jj = 0; jj < 4; ++jj) pk[jj] = f2bf(acc[i][r][jj] + bv);
          *(u16x4*)&sh[nl * 136 + mlb] = pk;
        }
      }
      __syncthreads();
      for (int it = 0; it < 4; ++it) {
        int nl = it * 32 + (tid >> 3);
        int c = (tid & 7) * 16;
        bf16x8 v0 = *(const bf16x8*)&sh[nl * 136 + c];
        bf16x8 v1 = *(const bf16x8*)&sh[nl * 136 + c + 8];
        int dk = nl & 63, hd = nl >> 6;
        size_t bh = (size_t)(b_idx * 16 + head0 + hd);
        size_t off = (bh * 64 + dk) * 2048 + l0 + c;
        *(bf16x8*)(Vt + off) = v0;
        *(bf16x8*)(Vt + off + 8) = v1;
      }
    }
  } else {
    for (int r = 0; r < 4; ++r) {
      int n = n0 + wc * 64 + r * 16 + lr;
      float bv = bias[n];
      for (int i = 0; i < 4; ++i) {
        int mb = m0 + wr * 64 + i * 16 + lg * 4;
        for (int jj = 0; jj < 4; ++jj)
          outF[(size_t)(mb + jj) * 1024 + n] = acc[i][r][jj] + bv;
      }
    }
  }
}

// ---------------- fused attention (v2: contiguous 1KB row stores) ----------------
// Block = 32 q-rows, 4 waves splitting the key dim (wave w does kts 4g+w).
// Per group g: P for 32 rows x 256 contiguous keys lands in shared [32][260]
// fp32 tile; store phase = one 1KB-contiguous nt f32x4 wave-store per row
// (fill-kernel pattern). PV partial per wave, cross-wave reduce at end.
// Grid 2048, XCD-bijective (bid&7). LDS ~34KB -> 4 blocks/CU -> 4 waves/SIMD.
__global__ __launch_bounds__(256) void k_attn(const unsigned short* __restrict__ Qb,
                                              const unsigned short* __restrict__ Kb,
                                              const unsigned short* __restrict__ Vt,
                                              float* __restrict__ attn,
                                              unsigned short* __restrict__ ctx) {
  __shared__ float Pf[32 * 260];
  __shared__ float Ls[4][32];
  __shared__ float Linv[32];
  int tid = threadIdx.x, lane = tid & 63, w = tid >> 6;
  int lr = lane & 15, lg = lane >> 4;
  int bid = blockIdx.x;
  int xcd = bid & 7, slot = bid >> 3;       // slot 0..255
  int bh = xcd * 4 + (slot >> 6);           // 4 heads per XCD
  int rb = slot & 63;
  int q0 = rb * 32;
  int b_idx = bh >> 4, h = bh & 15;
  const unsigned short* Qh = Qb + (size_t)bh * 2048 * 64;
  const unsigned short* Kh = Kb + (size_t)bh * 2048 * 64;
  const unsigned short* Vh = Vt + (size_t)bh * 64 * 2048;
  const float A2 = 0.125f * 1.44269504089f;  // scale * log2(e)

  // all 4 waves hold the SAME 32 q-rows in registers
  bf16x8 qf[2][2];
  for (int i = 0; i < 2; ++i)
    for (int kq = 0; kq < 2; ++kq)
      qf[i][kq] = *(const bf16x8*)(Qh + (size_t)(q0 + i * 16 + lr) * 64 + kq * 32 + lg * 8);

  float l_run[8] = {0.f, 0.f, 0.f, 0.f, 0.f, 0.f, 0.f, 0.f};

  // ---- pass 1: wave w sums exp over kts {4g+w} ----
  for (int g = 0; g < 8; ++g) {
    int kt = g * 4 + w;
    f32x4 acc[2][4] = {};
    for (int kq = 0; kq < 2; ++kq) {
      int kof = kq * 32 + lg * 8;
      bf16x8 kf[4];
      for (int r = 0; r < 4; ++r)
        kf[r] = *(const bf16x8*)(Kh + (size_t)(kt * 64 + r * 16 + lr) * 64 + kof);
      for (int i = 0; i < 2; ++i)
        for (int r = 0; r < 4; ++r)
          acc[i][r] = __builtin_amdgcn_mfma_f32_16x16x32_bf16(qf[i][kq], kf[r], acc[i][r], 0, 0, 0);
    }
    for (int i = 0; i < 2; ++i)
      for (int jj = 0; jj < 4; ++jj) {
        int z = i * 4 + jj;
        l_run[z] += fexp2(acc[i][0][jj] * A2) + fexp2(acc[i][1][jj] * A2) +
                    fexp2(acc[i][2][jj] * A2) + fexp2(acc[i][3][jj] * A2);
      }
  }
  // 16-lane reduce -> full row sums for this wave's kts; cross-wave via LDS
  for (int z = 0; z < 8; ++z) {
    float s = l_run[z];
    s += __shfl_xor(s, 1);
    s += __shfl_xor(s, 2);
    s += __shfl_xor(s, 4);
    s += __shfl_xor(s, 8);
    l_run[z] = s;
  }
  if (lr == 0)
    for (int i = 0; i < 2; ++i)
      for (int jj = 0; jj < 4; ++jj)
        Ls[w][i * 16 + lg * 4 + jj] = l_run[i * 4 + jj];
  __syncthreads();
  if (tid < 32)
    Linv[tid] = 1.0f / (Ls[0][tid] + Ls[1][tid] + Ls[2][tid] + Ls[3][tid]);
  __syncthreads();
  float invl[8];
  for (int i = 0; i < 2; ++i)
    for (int jj = 0; jj < 4; ++jj)
      invl[i * 4 + jj] = Linv[i * 16 + lg * 4 + jj];

  // ---- pass 2: per group, build [32][256] P tile, 1KB-contiguous stores, PV ----
  f32x4 cacc[2][4] = {};
  float* attn_row0 = attn + (size_t)bh * 2048 * 2048 + (size_t)q0 * 2048;

  for (int g = 0; g < 8; ++g) {
    int kt = g * 4 + w;
    f32x4 acc[2][4] = {};
    for (int kq = 0; kq < 2; ++kq) {
      int kof = kq * 32 + lg * 8;
      bf16x8 kf[4];
      for (int r = 0; r < 4; ++r)
        kf[r] = *(const bf16x8*)(Kh + (size_t)(kt * 64 + r * 16 + lr) * 64 + kof);
      for (int i = 0; i < 2; ++i)
        for (int r = 0; r < 4; ++r)
          acc[i][r] = __builtin_amdgcn_mfma_f32_16x16x32_bf16(qf[i][kq], kf[r], acc[i][r], 0, 0, 0);
    }
    for (int i = 0; i < 2; ++i)
      for (int r = 0; r < 4; ++r) {
        int col = w * 64 + r * 16 + lr;   // column within group's 256-key window
        for (int jj = 0; jj < 4; ++jj) {
          int z = i * 4 + jj;
          int rl = i * 16 + lg * 4 + jj;
          Pf[rl * 260 + col] = fexp2(acc[i][r][jj] * A2) * invl[z];
        }
      }
    __syncthreads();
    // store: wave w stores rows w*8..w*8+7; 1KB contiguous per instruction
    for (int s = 0; s < 8; ++s) {
      int row = w * 8 + s;
      f32x4 v = *(const f32x4*)&Pf[row * 260 + lane * 4];
      __builtin_nontemporal_store(v,
          (f32x4*)(attn_row0 + (size_t)row * 2048 + g * 256 + lane * 4));
    }
    // PV for this wave's kt: A = P cols w*64.., B = V^T rows
    for (int kq2 = 0; kq2 < 2; ++kq2) {
      int kof = kq2 * 32 + lg * 8;
      bf16x8 pa[2], vf[4];
      for (int i = 0; i < 2; ++i) {
        f32x4 plo = *(const f32x4*)&Pf[(i * 16 + lr) * 260 + w * 64 + kof];
        f32x4 phi = *(const f32x4*)&Pf[(i * 16 + lr) * 260 + w * 64 + kof + 4];
        pa[i] = pack8(plo, phi);
      }
      for (int nn = 0; nn < 4; ++nn)
        vf[nn] = *(const bf16x8*)(Vh + (size_t)(nn * 16 + lr) * 2048 + kt * 64 + kof);
      for (int i = 0; i < 2; ++i)
        for (int nn = 0; nn < 4; ++nn)
          cacc[i][nn] = __builtin_amdgcn_mfma_f32_16x16x32_bf16(pa[i], vf[nn], cacc[i][nn], 0, 0, 0);
    }
    __syncthreads();
  }

  // ---- epilogue: cross-wave ctx reduce (deterministic w-order) ----
  float* Cs = Pf;  // reuse: 4*32*64 = 8192 floats <= 8320
  for (int i = 0; i < 2; ++i)
    for (int nn = 0; nn < 4; ++nn)
      for (int jj = 0; jj < 4; ++jj)
        Cs[w * 2048 + (i * 16 + lg * 4 + jj) * 64 + nn * 16 + lr] = cacc[i][nn][jj];
  __syncthreads();
  {
    int base = tid * 8;
    int row = base >> 6, d0 = base & 63;
    float v[8];
    for (int j = 0; j < 8; ++j) {
      float s = Cs[base + j] + Cs[2048 + base + j] + Cs[4096 + base + j] + Cs[6144 + base + j];
      v[j] = s;
    }
    union { unsigned short us[8]; bf16x8 b; } pk;
    for (int j = 0; j < 8; ++j) pk.us[j] = f2bf(v[j]);
    int tok = b_idx * 2048 + q0 + row;
    *(bf16x8*)(ctx + (size_t)tok * 1024 + h * 64 + d0) = pk.b;
  }
}

extern "C" void kernel_launch(void* const* d_in, const int* in_sizes, int n_in,
                              void* d_out, int out_size, void* d_ws, size_t ws_size,
                              hipStream_t stream) {
  const float* x    = (const float*)d_in[0];
  const float* Wqkv = (const float*)d_in[1];
  const float* bqkv = (const float*)d_in[2];
  const float* Wo   = (const float*)d_in[3];
  const float* bo   = (const float*)d_in[4];
  float* out  = (float*)d_out;
  float* attn = out + (size_t)4096 * 1024;

  char* ws = (char*)d_ws;
  unsigned short* xbf = (unsigned short*)(ws);              //  8 MB  [4096][1024]
  unsigned short* wqT = (unsigned short*)(ws + 8388608);    //  6 MB  [3072][1024]
  unsigned short* woT = (unsigned short*)(ws + 14680064);   //  2 MB  [1024][1024]
  unsigned short* Qb  = (unsigned short*)(ws + 16777216);   //  8 MB  [32][2048][64]
  unsigned short* Kb  = (unsigned short*)(ws + 25165824);   //  8 MB  [32][2048][64]
  unsigned short* Vt  = (unsigned short*)(ws + 33554432);   //  8 MB  [32][64][2048]
  unsigned short* ctx = (unsigned short*)(ws + 41943040);   //  8 MB  [4096][1024]

  k_cast_x<<<dim3(4096), dim3(256), 0, stream>>>(x, xbf, 1048576);
  k_transpose_w<<<dim3(16, 48), dim3(256), 0, stream>>>(Wqkv, wqT, 1024, 3072);
  k_transpose_w<<<dim3(16, 16), dim3(256), 0, stream>>>(Wo, woT, 1024, 1024);
  k_gemm<0><<<dim3(32, 24), dim3(256), 0, stream>>>(xbf, wqT, bqkv, Qb, Kb, Vt, nullptr);
  k_attn<<<dim3(2048), dim3(256), 0, stream>>>(Qb, Kb, Vt, attn, ctx);
  k_gemm<1><<<dim3(32, 8), dim3(256), 0, stream>>>(ctx, woT, bo, nullptr, nullptr, nullptr, out);
}